// Round 3
// baseline (210.943 us; speedup 1.0000x reference)
//
#include <hip/hip_runtime.h>
#include <hip/hip_bf16.h>

typedef unsigned short u16;
typedef float f32x4 __attribute__((ext_vector_type(4)));

#define B_ 32
#define N_ 1024
#define D_ 512
#define K_ 64
#define KG_ 80

// ---------------------------------------------------------------------------
// K0: fold BN into affine sc/sh; zero the atomically-accumulated buffers.
// (all inputs fp32)
// ---------------------------------------------------------------------------
__global__ void k_prep(const float* __restrict__ bn_w, const float* __restrict__ bn_b,
                       const float* __restrict__ bn_m, const float* __restrict__ bn_v,
                       float* __restrict__ bn_sc, float* __restrict__ bn_sh,
                       float* __restrict__ asum, float* __restrict__ ssq) {
  int t = blockIdx.x * 256 + threadIdx.x;
  if (t < KG_) {
    float sc = bn_w[t] * rsqrtf(bn_v[t] + 1e-5f);
    bn_sc[t] = sc;
    bn_sh[t] = bn_b[t] - bn_m[t] * sc;
  }
  if (t < B_ * K_) asum[t] = 0.0f;
  if (t < B_) ssq[t] = 0.0f;
}

// ---------------------------------------------------------------------------
// K1: assignment = softmax(BN(x @ clusters))[:, :64]  +  a_sum[b,k]
// Block: 64 rows x 256 threads (4 waves); lane = row, wave owns 20 columns.
// x (fp32) staged in LDS in two 256-col chunks; f32x4 blocks XOR-swizzled
// (q' = q ^ (row&7)) on BOTH write and read -> full-BW ds_read_b128.
// Cluster reads are wave-uniform fp32 -> scalar-load path.
// Cross-wave softmax via per-wave (max, sum-exp) partials in LDS.
// ---------------------------------------------------------------------------
__global__ __launch_bounds__(256, 2) void k_assign(
    const float* __restrict__ x, const float* __restrict__ clusters,
    const float* __restrict__ bn_sc, const float* __restrict__ bn_sh,
    float* __restrict__ a_ws, float* __restrict__ asum_g) {
  __shared__ float xs[64 * 256];    // 64 rows x 256 cols (one d-chunk), swizzled
  __shared__ float red[64 * 9];     // per row: 4 maxes + 4 sums (pad to 9)

  int t = threadIdx.x;
  int lane = t & 63;
  int w = __builtin_amdgcn_readfirstlane(t >> 6);   // wave id, uniform
  int r0 = blockIdx.x * 64;
  int b = r0 >> 10;                 // 1024 rows per batch

  int j0 = w * 20;
  const float* cw = clusters + j0;
  float acc[20];
#pragma unroll
  for (int i = 0; i < 20; i++) acc[i] = 0.0f;
  int lsw = lane & 7;

  for (int c = 0; c < 2; c++) {
    __syncthreads();                // protect xs reuse between chunks
    const float* xg = x + (size_t)r0 * 512 + c * 256;
#pragma unroll
    for (int i = 0; i < 16; i++) {
      int e4 = t + i * 256;         // 0..4095 : 64 rows x 64 vec4-blocks
      int row = e4 >> 6;
      int q = e4 & 63;
      f32x4 v = *(const f32x4*)&xg[(size_t)row * 512 + q * 4];
      *(f32x4*)&xs[row * 256 + (q ^ (row & 7)) * 4] = v;
    }
    __syncthreads();

    const float* xrow = &xs[lane * 256];
    const float* cc = cw + (size_t)c * 256 * 80;
    for (int qb = 0; qb < 64; qb++) {
      f32x4 xv4 = *(const f32x4*)&xrow[(qb ^ lsw) * 4];
      const float* cp = cc + qb * 4 * 80;
#pragma unroll
      for (int j = 0; j < 4; j++) {
        float xv = xv4[j];
        const float* cj = cp + j * 80;
#pragma unroll
        for (int i = 0; i < 20; i++) acc[i] = fmaf(xv, cj[i], acc[i]);
      }
    }
  }

  // BN affine + wave-local softmax partials
  float lj[20], mw = -3.0e38f;
#pragma unroll
  for (int i = 0; i < 20; i++) {
    float l = fmaf(acc[i], bn_sc[j0 + i], bn_sh[j0 + i]);
    lj[i] = l;
    mw = fmaxf(mw, l);
  }
  float sw = 0.0f;
#pragma unroll
  for (int i = 0; i < 20; i++) { lj[i] = __expf(lj[i] - mw); sw += lj[i]; }

  red[lane * 9 + w] = mw;
  red[lane * 9 + 4 + w] = sw;
  __syncthreads();

  float M = fmaxf(fmaxf(red[lane * 9 + 0], red[lane * 9 + 1]),
                  fmaxf(red[lane * 9 + 2], red[lane * 9 + 3]));
  float S = 0.0f;
#pragma unroll
  for (int ww = 0; ww < 4; ww++)
    S += red[lane * 9 + 4 + ww] * __expf(red[lane * 9 + ww] - M);
  float f = __expf(mw - M) / S;

  int nkeep = (j0 < 60) ? 20 : 4;   // columns 64..79 are dropped
  float* arow = a_ws + (size_t)(r0 + lane) * 64 + j0;
  for (int i = 0; i < nkeep; i++) {
    float a = lj[i] * f;
    arow[i] = a;
    float s = a;                    // reduce over the 64 rows (lanes)
    s += __shfl_xor(s, 1);  s += __shfl_xor(s, 2);  s += __shfl_xor(s, 4);
    s += __shfl_xor(s, 8);  s += __shfl_xor(s, 16); s += __shfl_xor(s, 32);
    if (lane == 0) atomicAdd(&asum_g[b * 64 + j0 + i], s);
  }
}

// ---------------------------------------------------------------------------
// K2: vlad[b,d,k] = sum_n a[b,n,k]*x[b,n,d] - a_sum[b,k]*c2[d,k]
// One block per (b, d-tile of 64); bid = b + 32*dt keeps a batch's 8 tiles on
// one XCD (bid%8 = b%8) so a[b] (256KB) and x[b] cols are shared in L2.
// 256 threads, 4x4 fp32 acc each, 64-n LDS chunks. Fused block sum-of-squares.
// ---------------------------------------------------------------------------
__global__ __launch_bounds__(256, 2) void k_vlad(
    const float* __restrict__ x, const float* __restrict__ a_ws,
    const float* __restrict__ asum_g, const float* __restrict__ c2,
    float* __restrict__ vlad, float* __restrict__ ssq) {
  __shared__ float xs[64 * 68];     // [n][68] f32
  __shared__ float as[64 * 68];     // [n][68] f32
  __shared__ float wsum[4];

  int t = threadIdx.x;
  int bid = blockIdx.x;
  int b = bid & 31;
  int d0 = (bid >> 5) << 6;
  int kq = t & 15, dq = t >> 4;     // thread tile: d = d0+dq*4..+3, k = kq*4..+3
  float acc[4][4] = {{0.0f}};

  const float* xb = x + (size_t)b * 1024 * 512 + d0;
  const float* ab = a_ws + (size_t)b * 1024 * 64;
  int nl = t >> 2;
  int cx = (t & 3) * 16;

  for (int n0 = 0; n0 < 1024; n0 += 64) {
    f32x4 v0 = *(const f32x4*)&xb[(size_t)(n0 + nl) * 512 + cx];
    f32x4 v1 = *(const f32x4*)&xb[(size_t)(n0 + nl) * 512 + cx + 4];
    f32x4 v2 = *(const f32x4*)&xb[(size_t)(n0 + nl) * 512 + cx + 8];
    f32x4 v3 = *(const f32x4*)&xb[(size_t)(n0 + nl) * 512 + cx + 12];
    f32x4 a0 = *(const f32x4*)&ab[(n0 + nl) * 64 + cx];
    f32x4 a1 = *(const f32x4*)&ab[(n0 + nl) * 64 + cx + 4];
    f32x4 a2 = *(const f32x4*)&ab[(n0 + nl) * 64 + cx + 8];
    f32x4 a3 = *(const f32x4*)&ab[(n0 + nl) * 64 + cx + 12];
    *(f32x4*)&xs[nl * 68 + cx]      = v0;
    *(f32x4*)&xs[nl * 68 + cx + 4]  = v1;
    *(f32x4*)&xs[nl * 68 + cx + 8]  = v2;
    *(f32x4*)&xs[nl * 68 + cx + 12] = v3;
    *(f32x4*)&as[nl * 68 + cx]      = a0;
    *(f32x4*)&as[nl * 68 + cx + 4]  = a1;
    *(f32x4*)&as[nl * 68 + cx + 8]  = a2;
    *(f32x4*)&as[nl * 68 + cx + 12] = a3;
    __syncthreads();

#pragma unroll 4
    for (int n = 0; n < 64; n++) {
      f32x4 xr = *(const f32x4*)&xs[n * 68 + dq * 4];
      f32x4 ar = *(const f32x4*)&as[n * 68 + kq * 4];
#pragma unroll
      for (int i = 0; i < 4; i++) {
#pragma unroll
        for (int j = 0; j < 4; j++) acc[i][j] = fmaf(xr[i], ar[j], acc[i][j]);
      }
    }
    __syncthreads();
  }

  // epilogue: subtract a_sum*c2, write fp32 vlad, accumulate sum of squares
  float asv[4];
#pragma unroll
  for (int j = 0; j < 4; j++) asv[j] = asum_g[b * 64 + kq * 4 + j];
  float lssq = 0.0f;
  size_t obase = ((size_t)b * 512 + d0 + dq * 4) * 64 + kq * 4;
#pragma unroll
  for (int i = 0; i < 4; i++) {
    f32x4 cv = *(const f32x4*)&c2[(size_t)(d0 + dq * 4 + i) * 64 + kq * 4];
    f32x4 o;
#pragma unroll
    for (int j = 0; j < 4; j++) {
      float val = acc[i][j] - asv[j] * cv[j];
      o[j] = val;
      lssq += val * val;
    }
    *(f32x4*)&vlad[obase + (size_t)i * 64] = o;
  }
  lssq += __shfl_xor(lssq, 1);  lssq += __shfl_xor(lssq, 2);
  lssq += __shfl_xor(lssq, 4);  lssq += __shfl_xor(lssq, 8);
  lssq += __shfl_xor(lssq, 16); lssq += __shfl_xor(lssq, 32);
  if ((t & 63) == 0) wsum[t >> 6] = lssq;
  __syncthreads();
  if (t == 0) atomicAdd(&ssq[b], wsum[0] + wsum[1] + wsum[2] + wsum[3]);
}

// ---------------------------------------------------------------------------
// K3: fold both L2 normalizations into one per-batch scale.
// n1 = sqrt(S+eps); after y=v/n1, sum y^2 = S/(S+eps); n2 = sqrt(that+eps).
// ---------------------------------------------------------------------------
__global__ void k_scale(const float* __restrict__ ssq, float* __restrict__ scale) {
  int t = threadIdx.x;
  if (t < B_) {
    float S = ssq[t];
    float n1 = sqrtf(S + 1e-12f);
    float n2 = sqrtf(S / (S + 1e-12f) + 1e-12f);
    scale[t] = 1.0f / (n1 * n2);
  }
}

// ---------------------------------------------------------------------------
// K4: out = fp32(vlad * scale[b])   — reference output dtype is float32
// ---------------------------------------------------------------------------
__global__ __launch_bounds__(256) void k_out(const float* __restrict__ vlad,
                                             const float* __restrict__ scale,
                                             float* __restrict__ out) {
  int idx = blockIdx.x * 256 + threadIdx.x;   // 4 elems per thread
  float s = scale[idx >> 13];                 // 32768 elems per batch
  f32x4 v = *(const f32x4*)&vlad[(size_t)idx * 4];
  f32x4 o;
#pragma unroll
  for (int j = 0; j < 4; j++) o[j] = v[j] * s;
  *(f32x4*)&out[(size_t)idx * 4] = o;
}

extern "C" void kernel_launch(void* const* d_in, const int* in_sizes, int n_in,
                              void* d_out, int out_size, void* d_ws, size_t ws_size,
                              hipStream_t stream) {
  const float* x        = (const float*)d_in[0];
  const float* clusters = (const float*)d_in[1];
  const float* clusters2= (const float*)d_in[2];
  const float* bn_w     = (const float*)d_in[3];
  const float* bn_b     = (const float*)d_in[4];
  const float* bn_m     = (const float*)d_in[5];
  const float* bn_v     = (const float*)d_in[6];
  float* out = (float*)d_out;

  char* ws = (char*)d_ws;
  float* a_ws  = (float*)ws;                          // 32768*64 f32 = 8 MB
  float* vlad  = (float*)(ws + (size_t)8 * 1048576);  // 32*512*64 f32 = 4 MB
  float* bn_sc = (float*)(ws + (size_t)12 * 1048576); // 80 f32
  float* bn_sh = bn_sc + KG_;
  float* asum  = bn_sh + KG_;                         // 32*64 f32
  float* ssq   = asum + B_ * K_;                      // 32 f32
  float* scale = ssq + B_;                            // 32 f32

  k_prep<<<8, 256, 0, stream>>>(bn_w, bn_b, bn_m, bn_v,
                                bn_sc, bn_sh, asum, ssq);
  k_assign<<<512, 256, 0, stream>>>(x, clusters, bn_sc, bn_sh, a_ws, asum);
  k_vlad<<<256, 256, 0, stream>>>(x, a_ws, asum, clusters2, vlad, ssq);
  k_scale<<<1, 64, 0, stream>>>(ssq, scale);
  k_out<<<1024, 256, 0, stream>>>(vlad, scale, out);
}